// Round 1
// baseline (1616.579 us; speedup 1.0000x reference)
//
#include <hip/hip_runtime.h>
#include <hip/hip_bf16.h>
#include <stdint.h>

// DBRX attention block: qkv proj (+clamp) -> RoPE -> causal GQA flash attn -> out proj.
// B=2 S=2048 D=4096 NH=32 NKV=8 HD=128. All GEMM-shaped compute in bf16 MFMA, fp32 accum.

#define B_ 2
#define S_ 2048
#define D_ 4096
#define NH_ 32
#define NKV_ 8
#define HD_ 128
#define QKVN 6144           // D + 2*NKV*HD
#define SCALE_ 0.08838834764831845f   // 128^-0.5
#define LOG2E 1.44269504f

typedef unsigned short ushort_t;
typedef __attribute__((ext_vector_type(8))) short bf16x8;
typedef __attribute__((ext_vector_type(4))) float f32x4;
typedef __attribute__((ext_vector_type(4))) unsigned short us4;
typedef __attribute__((ext_vector_type(8))) unsigned short us8;

__device__ __forceinline__ float bf2f(unsigned short s) {
  union { unsigned u; float f; } v; v.u = ((unsigned)s) << 16; return v.f;
}
__device__ __forceinline__ unsigned short f2bf(float f) {
  union { float f; unsigned u; } v; v.f = f;
  unsigned r = v.u + 0x7FFFu + ((v.u >> 16) & 1u);   // RNE, finite inputs only
  return (unsigned short)(r >> 16);
}

// ---------------- f32 -> bf16 convert (8 elems/thread/iter) ----------------
__global__ __launch_bounds__(256) void f2bf_kernel(const float* __restrict__ in,
                                                   ushort_t* __restrict__ out, int n8) {
  int stride = gridDim.x * blockDim.x;
  for (int i = blockIdx.x * blockDim.x + threadIdx.x; i < n8; i += stride) {
    float4 a = ((const float4*)in)[2 * i];
    float4 b = ((const float4*)in)[2 * i + 1];
    us8 o;
    o[0] = f2bf(a.x); o[1] = f2bf(a.y); o[2] = f2bf(a.z); o[3] = f2bf(a.w);
    o[4] = f2bf(b.x); o[5] = f2bf(b.y); o[6] = f2bf(b.z); o[7] = f2bf(b.w);
    ((us8*)out)[i] = o;
  }
}

// ---------------- bf16 GEMM, C = A[M,K] * B[N,K]^T (m97 structure) ----------------
// 128x128 tile, BK=32, 256 thr = 4 waves (2x2), each wave 64x64 = 4x4 16x16 frags.
// EPI==0: clamp(+-8) -> bf16 store (QKV).  EPI==1: f32 store (out proj).
typedef const __attribute__((address_space(1))) unsigned int GAS1;
typedef __attribute__((address_space(3))) unsigned int LAS3;

template <int EPI>
__global__ __launch_bounds__(256) void gemm_bt(const ushort_t* __restrict__ A,
                                               const ushort_t* __restrict__ B,
                                               void* __restrict__ C,
                                               int M, int N, int K) {
  __shared__ ushort_t sA[128 * 32];
  __shared__ ushort_t sB[128 * 32];
  const int tid = threadIdx.x;
  const int lane = tid & 63;
  const int wid = tid >> 6;
  const long bm = (long)blockIdx.y * 128;
  const long bn = (long)blockIdx.x * 128;
  const int wr = wid >> 1, wc = wid & 1;
  const int fr = lane & 15, fg = lane >> 4;

  // staging: 8 chunks of 1024B per tile; wave handles chunks {wid, wid+4}
  const int srow = lane >> 2;            // 0..15 within chunk
  const int scol = (lane & 3) * 8;       // 0,8,16,24
  const ushort_t* gA1 = A + (bm + wid * 16 + srow) * K + scol;
  const ushort_t* gA2 = A + (bm + (wid + 4) * 16 + srow) * K + scol;
  const ushort_t* gB1 = B + (bn + wid * 16 + srow) * K + scol;
  const ushort_t* gB2 = B + (bn + (wid + 4) * 16 + srow) * K + scol;

  f32x4 acc[4][4] = {};
  const int nK = K >> 5;
  for (int kt = 0; kt < nK; ++kt) {
    __builtin_amdgcn_global_load_lds((GAS1*)gA1, (LAS3*)((char*)sA + wid * 1024), 16, 0, 0);
    __builtin_amdgcn_global_load_lds((GAS1*)gA2, (LAS3*)((char*)sA + (wid + 4) * 1024), 16, 0, 0);
    __builtin_amdgcn_global_load_lds((GAS1*)gB1, (LAS3*)((char*)sB + wid * 1024), 16, 0, 0);
    __builtin_amdgcn_global_load_lds((GAS1*)gB2, (LAS3*)((char*)sB + (wid + 4) * 1024), 16, 0, 0);
    gA1 += 32; gA2 += 32; gB1 += 32; gB2 += 32;
    __syncthreads();
    bf16x8 af[4], bfr[4];
#pragma unroll
    for (int m = 0; m < 4; ++m)
      af[m] = *(const bf16x8*)(sA + (wr * 64 + m * 16 + fr) * 32 + fg * 8);
#pragma unroll
    for (int n = 0; n < 4; ++n)
      bfr[n] = *(const bf16x8*)(sB + (wc * 64 + n * 16 + fr) * 32 + fg * 8);
#pragma unroll
    for (int m = 0; m < 4; ++m)
#pragma unroll
      for (int n = 0; n < 4; ++n)
        acc[m][n] = __builtin_amdgcn_mfma_f32_16x16x32_bf16(af[m], bfr[n], acc[m][n], 0, 0, 0);
    __syncthreads();
  }
  // epilogue: C/D layout col = lane&15, row = (lane>>4)*4 + r
  const long crow = bm + wr * 64 + fg * 4;
  const long ccol = bn + wc * 64 + fr;
#pragma unroll
  for (int m = 0; m < 4; ++m)
#pragma unroll
    for (int n = 0; n < 4; ++n)
#pragma unroll
      for (int r = 0; r < 4; ++r) {
        long row = crow + m * 16 + r;
        long col = ccol + n * 16;
        float v = acc[m][n][r];
        if (EPI == 0) {
          v = fminf(fmaxf(v, -8.0f), 8.0f);
          ((ushort_t*)C)[row * N + col] = f2bf(v);
        } else {
          ((float*)C)[row * N + col] = v;
        }
      }
}

// ---------------- RoPE + split qkv -> Q[B,NH,S,HD], K[B,NKV,S,HD], V[B,NKV,S,HD] ----------------
__global__ __launch_bounds__(256) void rope_split(const ushort_t* __restrict__ qkv,
                                                  const float* __restrict__ cosb,
                                                  const float* __restrict__ sinb,
                                                  ushort_t* __restrict__ Qo,
                                                  ushort_t* __restrict__ Ko,
                                                  ushort_t* __restrict__ Vo) {
  const int row = blockIdx.x;  // b*S + s
  const int b = row >> 11;
  const int s = row & (S_ - 1);
  const int t = threadIdx.x;
  const ushort_t* qrow = qkv + (long)row * QKVN;
#pragma unroll
  for (int i = 0; i < 8; ++i) {  // Q: 32 heads * 64 pairs
    int p = i * 256 + t;
    int h = p >> 6, d = p & 63;
    float q1 = bf2f(qrow[h * 128 + d]);
    float q2 = bf2f(qrow[h * 128 + d + 64]);
    float c = cosb[s * HD_ + d];
    float sn = sinb[s * HD_ + d];
    long base = ((long)(b * NH_ + h) * S_ + s) * HD_ + d;
    Qo[base] = f2bf(q1 * c - q2 * sn);
    Qo[base + 64] = f2bf(q2 * c + q1 * sn);
  }
#pragma unroll
  for (int i = 0; i < 2; ++i) {  // K: 8 heads * 64 pairs
    int p = i * 256 + t;
    int h = p >> 6, d = p & 63;
    float k1 = bf2f(qrow[D_ + h * 128 + d]);
    float k2 = bf2f(qrow[D_ + h * 128 + d + 64]);
    float c = cosb[s * HD_ + d];
    float sn = sinb[s * HD_ + d];
    long base = ((long)(b * NKV_ + h) * S_ + s) * HD_ + d;
    Ko[base] = f2bf(k1 * c - k2 * sn);
    Ko[base + 64] = f2bf(k2 * c + k1 * sn);
  }
#pragma unroll
  for (int i = 0; i < 4; ++i) {  // V: plain copy
    int e = i * 256 + t;
    int h = e >> 7, d = e & 127;
    Vo[((long)(b * NKV_ + h) * S_ + s) * HD_ + d] = qrow[D_ + NKV_ * HD_ + e];
  }
}

// ---------------- V transpose: [BH, S, HD] -> [BH, HD, S] ----------------
__global__ __launch_bounds__(256) void transpose_v(const ushort_t* __restrict__ V,
                                                   ushort_t* __restrict__ Vt) {
  __shared__ ushort_t tile[32][36];
  const int bh = blockIdx.z;
  const int s0 = blockIdx.y * 32, d0 = blockIdx.x * 32;
  const int t = threadIdx.x;
  const int r = t >> 3, c4 = (t & 7) * 4;
  us4 v = *(const us4*)(V + ((long)bh * S_ + s0 + r) * HD_ + d0 + c4);
  tile[r][c4] = v[0]; tile[r][c4 + 1] = v[1]; tile[r][c4 + 2] = v[2]; tile[r][c4 + 3] = v[3];
  __syncthreads();
  us4 w;
  w[0] = tile[c4][r]; w[1] = tile[c4 + 1][r]; w[2] = tile[c4 + 2][r]; w[3] = tile[c4 + 3][r];
  *(us4*)(Vt + ((long)bh * HD_ + d0 + r) * S_ + s0 + c4) = w;
}

// ---------------- causal GQA flash attention ----------------
// block = (qtile 64 rows, head, batch); 4 waves x 16 q-rows; KV tiles of 32.
// scores: A=Q(16x32 over d), B=K (B^T layout). P via per-wave LDS C->A relayout.
// PV: B-operand from Vt [HD][S] (contiguous in kv). Output [B,S,NH,HD] bf16.
__global__ __launch_bounds__(256) void attn_fwd(const ushort_t* __restrict__ Q,
                                                const ushort_t* __restrict__ K,
                                                const ushort_t* __restrict__ Vt,
                                                ushort_t* __restrict__ O) {
  const int tid = threadIdx.x;
  const int lane = tid & 63, w = tid >> 6;
  const int fr = lane & 15, fg = lane >> 4;
  const int qt = blockIdx.x, h = blockIdx.y, b = blockIdx.z;
  const int hk = h >> 2;
  const int qbase = qt * 64 + w * 16;
  const ushort_t* Qp = Q + ((long)(b * NH_ + h) * S_) * HD_;
  const ushort_t* Kp = K + ((long)(b * NKV_ + hk) * S_) * HD_;
  const ushort_t* Vp = Vt + ((long)(b * NKV_ + hk) * HD_) * S_;
  __shared__ ushort_t Plds[4][16][32];

  // Q fragments (scaled by SCALE_), 4 d-chunks of 32
  bf16x8 qf[4];
#pragma unroll
  for (int dk = 0; dk < 4; ++dk) {
    bf16x8 tq = *(const bf16x8*)(Qp + (long)(qbase + fr) * HD_ + dk * 32 + fg * 8);
#pragma unroll
    for (int j = 0; j < 8; ++j)
      tq[j] = (short)f2bf(bf2f((unsigned short)tq[j]) * SCALE_);
    qf[dk] = tq;
  }
  f32x4 o[8];
  float m[4], l[4];
#pragma unroll
  for (int i = 0; i < 8; ++i) o[i] = (f32x4){0.f, 0.f, 0.f, 0.f};
#pragma unroll
  for (int r = 0; r < 4; ++r) { m[r] = -1e30f; l[r] = 0.f; }

  const int ntiles = ((qbase + 15) >> 5) + 1;
  for (int tkv = 0; tkv < ntiles; ++tkv) {
    const int kv0 = tkv * 32;
    f32x4 sc[2];
#pragma unroll
    for (int n = 0; n < 2; ++n) {
      f32x4 a = {0.f, 0.f, 0.f, 0.f};
      const ushort_t* kp = Kp + (long)(kv0 + n * 16 + fr) * HD_ + fg * 8;
#pragma unroll
      for (int dk = 0; dk < 4; ++dk) {
        bf16x8 kf = *(const bf16x8*)(kp + dk * 32);
        a = __builtin_amdgcn_mfma_f32_16x16x32_bf16(qf[dk], kf, a, 0, 0, 0);
      }
      sc[n] = a;
    }
    if (kv0 + 31 > qbase) {  // causal mask needed
#pragma unroll
      for (int n = 0; n < 2; ++n) {
        int kj = kv0 + n * 16 + fr;
#pragma unroll
        for (int r = 0; r < 4; ++r) {
          int qi = qbase + fg * 4 + r;
          if (kj > qi) sc[n][r] = -1e30f;
        }
      }
    }
    float sca[4], p0[4], p1[4];
#pragma unroll
    for (int r = 0; r < 4; ++r) {
      float tm = fmaxf(sc[0][r], sc[1][r]);
      tm = fmaxf(tm, __shfl_xor(tm, 1));
      tm = fmaxf(tm, __shfl_xor(tm, 2));
      tm = fmaxf(tm, __shfl_xor(tm, 4));
      tm = fmaxf(tm, __shfl_xor(tm, 8));
      float nm = fmaxf(m[r], tm);
      sca[r] = exp2f((m[r] - nm) * LOG2E);
      m[r] = nm;
      p0[r] = exp2f((sc[0][r] - nm) * LOG2E);
      p1[r] = exp2f((sc[1][r] - nm) * LOG2E);
      float s2 = p0[r] + p1[r];
      s2 += __shfl_xor(s2, 1);
      s2 += __shfl_xor(s2, 2);
      s2 += __shfl_xor(s2, 4);
      s2 += __shfl_xor(s2, 8);
      l[r] = l[r] * sca[r] + s2;
    }
#pragma unroll
    for (int f = 0; f < 8; ++f)
#pragma unroll
      for (int r = 0; r < 4; ++r) o[f][r] *= sca[r];
    // P: C-layout -> LDS -> A-layout (per-wave private; no block barrier needed)
#pragma unroll
    for (int r = 0; r < 4; ++r) {
      Plds[w][fg * 4 + r][fr] = f2bf(p0[r]);
      Plds[w][fg * 4 + r][16 + fr] = f2bf(p1[r]);
    }
    asm volatile("s_waitcnt lgkmcnt(0)" ::: "memory");
    bf16x8 pa = *(const bf16x8*)(&Plds[w][fr][fg * 8]);
#pragma unroll
    for (int df = 0; df < 8; ++df) {
      const ushort_t* vp = Vp + (long)(df * 16 + fr) * S_ + kv0 + fg * 8;
      bf16x8 vf = *(const bf16x8*)vp;
      o[df] = __builtin_amdgcn_mfma_f32_16x16x32_bf16(pa, vf, o[df], 0, 0, 0);
    }
  }
#pragma unroll
  for (int df = 0; df < 8; ++df)
#pragma unroll
    for (int r = 0; r < 4; ++r) {
      int qi = qbase + fg * 4 + r;
      float v = o[df][r] / l[r];
      O[(((long)b * S_ + qi) * NH_ + h) * HD_ + df * 16 + fr] = f2bf(v);
    }
}

// ---------------- orchestration ----------------
extern "C" void kernel_launch(void* const* d_in, const int* in_sizes, int n_in,
                              void* d_out, int out_size, void* d_ws, size_t ws_size,
                              hipStream_t stream) {
  const float* hs = (const float*)d_in[0];
  const float* wqkv = (const float*)d_in[1];
  const float* wout = (const float*)d_in[2];
  const float* cosb = (const float*)d_in[3];
  const float* sinb = (const float*)d_in[4];
  char* ws = (char*)d_ws;

  // ws layout (128 MiB total, with lifetime-based aliasing):
  //  [0,33.5M):        hs_bf16      -> (after qkv gemm) Q
  //  [33.5M,83.9M):    wqkv_bf16    -> (after qkv gemm) K | V | Vt | attnout(spills to 92.3M)
  //  [83.9M,134.2M):   qkv_bf16     -> (after rope) tail reused for wout_bf16
  ushort_t* hsB = (ushort_t*)(ws + 0);
  ushort_t* wqB = (ushort_t*)(ws + 33554432);
  ushort_t* Kb = (ushort_t*)(ws + 33554432);
  ushort_t* Vb = (ushort_t*)(ws + 41943040);
  ushort_t* Vtb = (ushort_t*)(ws + 50331648);
  ushort_t* aoB = (ushort_t*)(ws + 58720256);
  ushort_t* qkvB = (ushort_t*)(ws + 83886080);
  ushort_t* woB = (ushort_t*)(ws + 100663296);
  ushort_t* Qb = hsB;

  hipLaunchKernelGGL(f2bf_kernel, dim3(2048), dim3(256), 0, stream, hs, hsB, 16777216 / 8);
  hipLaunchKernelGGL(f2bf_kernel, dim3(2048), dim3(256), 0, stream, wqkv, wqB, 25165824 / 8);
  hipLaunchKernelGGL((gemm_bt<0>), dim3(48, 32), dim3(256), 0, stream,
                     hsB, wqB, (void*)qkvB, 4096, QKVN, 4096);
  hipLaunchKernelGGL(rope_split, dim3(4096), dim3(256), 0, stream, qkvB, cosb, sinb, Qb, Kb, Vb);
  hipLaunchKernelGGL(f2bf_kernel, dim3(2048), dim3(256), 0, stream, wout, woB, 16777216 / 8);
  hipLaunchKernelGGL(transpose_v, dim3(4, 64, 16), dim3(256), 0, stream, Vb, Vtb);
  hipLaunchKernelGGL(attn_fwd, dim3(32, 32, 2), dim3(256), 0, stream, Qb, Kb, Vtb, aoB);
  hipLaunchKernelGGL((gemm_bt<1>), dim3(32, 32), dim3(256), 0, stream,
                     aoB, woB, d_out, 4096, 4096, 4096);
}

// Round 2
// 987.194 us; speedup vs baseline: 1.6376x; 1.6376x over previous
//
#include <hip/hip_runtime.h>
#include <hip/hip_bf16.h>
#include <stdint.h>

// DBRX attention block: qkv proj (+clamp) -> RoPE -> causal GQA flash attn -> out proj.
// B=2 S=2048 D=4096 NH=32 NKV=8 HD=128. All GEMM-shaped compute in bf16 MFMA, fp32 accum.

#define B_ 2
#define S_ 2048
#define D_ 4096
#define NH_ 32
#define NKV_ 8
#define HD_ 128
#define QKVN 6144           // D + 2*NKV*HD
#define SCALE_ 0.08838834764831845f   // 128^-0.5
#define LOG2E 1.44269504f

typedef unsigned short ushort_t;
typedef __attribute__((ext_vector_type(8))) short bf16x8;
typedef __attribute__((ext_vector_type(4))) float f32x4;
typedef __attribute__((ext_vector_type(4))) unsigned short us4;
typedef __attribute__((ext_vector_type(8))) unsigned short us8;

__device__ __forceinline__ float bf2f(unsigned short s) {
  union { unsigned u; float f; } v; v.u = ((unsigned)s) << 16; return v.f;
}
__device__ __forceinline__ unsigned short f2bf(float f) {
  union { float f; unsigned u; } v; v.f = f;
  unsigned r = v.u + 0x7FFFu + ((v.u >> 16) & 1u);   // RNE, finite inputs only
  return (unsigned short)(r >> 16);
}

// ---------------- f32 -> bf16 convert (8 elems/thread/iter) ----------------
__global__ __launch_bounds__(256) void f2bf_kernel(const float* __restrict__ in,
                                                   ushort_t* __restrict__ out, int n8) {
  int stride = gridDim.x * blockDim.x;
  for (int i = blockIdx.x * blockDim.x + threadIdx.x; i < n8; i += stride) {
    float4 a = ((const float4*)in)[2 * i];
    float4 b = ((const float4*)in)[2 * i + 1];
    us8 o;
    o[0] = f2bf(a.x); o[1] = f2bf(a.y); o[2] = f2bf(a.z); o[3] = f2bf(a.w);
    o[4] = f2bf(b.x); o[5] = f2bf(b.y); o[6] = f2bf(b.z); o[7] = f2bf(b.w);
    ((us8*)out)[i] = o;
  }
}

// ---------------- bf16 GEMM, C = A[M,K] * B[N,K]^T (m97 structure) ----------------
typedef const __attribute__((address_space(1))) unsigned int GAS1;
typedef __attribute__((address_space(3))) unsigned int LAS3;

template <int EPI>
__global__ __launch_bounds__(256) void gemm_bt(const ushort_t* __restrict__ A,
                                               const ushort_t* __restrict__ B,
                                               void* __restrict__ C,
                                               int M, int N, int K) {
  __shared__ ushort_t sA[128 * 32];
  __shared__ ushort_t sB[128 * 32];
  const int tid = threadIdx.x;
  const int lane = tid & 63;
  const int wid = tid >> 6;
  const long bm = (long)blockIdx.y * 128;
  const long bn = (long)blockIdx.x * 128;
  const int wr = wid >> 1, wc = wid & 1;
  const int fr = lane & 15, fg = lane >> 4;

  const int srow = lane >> 2;
  const int scol = (lane & 3) * 8;
  const ushort_t* gA1 = A + (bm + wid * 16 + srow) * K + scol;
  const ushort_t* gA2 = A + (bm + (wid + 4) * 16 + srow) * K + scol;
  const ushort_t* gB1 = B + (bn + wid * 16 + srow) * K + scol;
  const ushort_t* gB2 = B + (bn + (wid + 4) * 16 + srow) * K + scol;

  f32x4 acc[4][4] = {};
  const int nK = K >> 5;
  for (int kt = 0; kt < nK; ++kt) {
    __builtin_amdgcn_global_load_lds((GAS1*)gA1, (LAS3*)((char*)sA + wid * 1024), 16, 0, 0);
    __builtin_amdgcn_global_load_lds((GAS1*)gA2, (LAS3*)((char*)sA + (wid + 4) * 1024), 16, 0, 0);
    __builtin_amdgcn_global_load_lds((GAS1*)gB1, (LAS3*)((char*)sB + wid * 1024), 16, 0, 0);
    __builtin_amdgcn_global_load_lds((GAS1*)gB2, (LAS3*)((char*)sB + (wid + 4) * 1024), 16, 0, 0);
    gA1 += 32; gA2 += 32; gB1 += 32; gB2 += 32;
    __syncthreads();
    bf16x8 af[4], bfr[4];
#pragma unroll
    for (int m = 0; m < 4; ++m)
      af[m] = *(const bf16x8*)(sA + (wr * 64 + m * 16 + fr) * 32 + fg * 8);
#pragma unroll
    for (int n = 0; n < 4; ++n)
      bfr[n] = *(const bf16x8*)(sB + (wc * 64 + n * 16 + fr) * 32 + fg * 8);
#pragma unroll
    for (int m = 0; m < 4; ++m)
#pragma unroll
      for (int n = 0; n < 4; ++n)
        acc[m][n] = __builtin_amdgcn_mfma_f32_16x16x32_bf16(af[m], bfr[n], acc[m][n], 0, 0, 0);
    __syncthreads();
  }
  const long crow = bm + wr * 64 + fg * 4;
  const long ccol = bn + wc * 64 + fr;
#pragma unroll
  for (int m = 0; m < 4; ++m)
#pragma unroll
    for (int n = 0; n < 4; ++n)
#pragma unroll
      for (int r = 0; r < 4; ++r) {
        long row = crow + m * 16 + r;
        long col = ccol + n * 16;
        float v = acc[m][n][r];
        if (EPI == 0) {
          v = fminf(fmaxf(v, -8.0f), 8.0f);
          ((ushort_t*)C)[row * N + col] = f2bf(v);
        } else {
          ((float*)C)[row * N + col] = v;
        }
      }
}

// ---------------- RoPE + split qkv -> Q[B,NH,S,HD], K[B,NKV,S,HD], V[B,NKV,S,HD] ----------------
__global__ __launch_bounds__(256) void rope_split(const ushort_t* __restrict__ qkv,
                                                  const float* __restrict__ cosb,
                                                  const float* __restrict__ sinb,
                                                  ushort_t* __restrict__ Qo,
                                                  ushort_t* __restrict__ Ko,
                                                  ushort_t* __restrict__ Vo) {
  const int row = blockIdx.x;  // b*S + s
  const int b = row >> 11;
  const int s = row & (S_ - 1);
  const int t = threadIdx.x;
  const ushort_t* qrow = qkv + (long)row * QKVN;
#pragma unroll
  for (int i = 0; i < 8; ++i) {
    int p = i * 256 + t;
    int h = p >> 6, d = p & 63;
    float q1 = bf2f(qrow[h * 128 + d]);
    float q2 = bf2f(qrow[h * 128 + d + 64]);
    float c = cosb[s * HD_ + d];
    float sn = sinb[s * HD_ + d];
    long base = ((long)(b * NH_ + h) * S_ + s) * HD_ + d;
    Qo[base] = f2bf(q1 * c - q2 * sn);
    Qo[base + 64] = f2bf(q2 * c + q1 * sn);
  }
#pragma unroll
  for (int i = 0; i < 2; ++i) {
    int p = i * 256 + t;
    int h = p >> 6, d = p & 63;
    float k1 = bf2f(qrow[D_ + h * 128 + d]);
    float k2 = bf2f(qrow[D_ + h * 128 + d + 64]);
    float c = cosb[s * HD_ + d];
    float sn = sinb[s * HD_ + d];
    long base = ((long)(b * NKV_ + h) * S_ + s) * HD_ + d;
    Ko[base] = f2bf(k1 * c - k2 * sn);
    Ko[base + 64] = f2bf(k2 * c + k1 * sn);
  }
#pragma unroll
  for (int i = 0; i < 4; ++i) {
    int e = i * 256 + t;
    int h = e >> 7, d = e & 127;
    Vo[((long)(b * NKV_ + h) * S_ + s) * HD_ + d] = qrow[D_ + NKV_ * HD_ + e];
  }
}

// ---------------- V transpose: [BH, S, HD] -> [BH, HD, S] ----------------
__global__ __launch_bounds__(256) void transpose_v(const ushort_t* __restrict__ V,
                                                   ushort_t* __restrict__ Vt) {
  __shared__ ushort_t tile[32][36];
  const int bh = blockIdx.z;
  const int s0 = blockIdx.y * 32, d0 = blockIdx.x * 32;
  const int t = threadIdx.x;
  const int r = t >> 3, c4 = (t & 7) * 4;
  us4 v = *(const us4*)(V + ((long)bh * S_ + s0 + r) * HD_ + d0 + c4);
  tile[r][c4] = v[0]; tile[r][c4 + 1] = v[1]; tile[r][c4 + 2] = v[2]; tile[r][c4 + 3] = v[3];
  __syncthreads();
  us4 w;
  w[0] = tile[c4][r]; w[1] = tile[c4 + 1][r]; w[2] = tile[c4 + 2][r]; w[3] = tile[c4 + 3][r];
  *(us4*)(Vt + ((long)bh * HD_ + d0 + r) * S_ + s0 + c4) = w;
}

// ---------------- causal GQA flash attention (LDS-staged, KVBLK=64) ----------------
// Block: 128 q rows (4 waves x 32), head, batch. K/V tiles staged to LDS via
// global_load_lds with XOR-swizzled layouts (linear dest + inverse-swizzled global
// source + swizzled ds_read). Row-sum of P computed by an extra ones-B MFMA
// accumulator (o[m][8]) -- no sum shuffles. Fully-masked tiles skipped per-wave.
__global__ __launch_bounds__(256, 2) void attn_fwd(const ushort_t* __restrict__ Q,
                                                   const ushort_t* __restrict__ K,
                                                   const ushort_t* __restrict__ Vt,
                                                   ushort_t* __restrict__ O) {
  const int tid = threadIdx.x;
  const int lane = tid & 63, w = tid >> 6;
  const int fr = lane & 15, fg = lane >> 4;
  const int qt = blockIdx.x, h = blockIdx.y, b = blockIdx.z;
  const int hk = h >> 2;
  const int qbase = qt * 128 + w * 32;
  const ushort_t* __restrict__ Qp = Q + ((long)(b * NH_ + h) * S_) * HD_;
  const ushort_t* __restrict__ Kp = K + ((long)(b * NKV_ + hk) * S_) * HD_;
  const ushort_t* __restrict__ Vp = Vt + ((long)(b * NKV_ + hk) * HD_) * S_;

  __shared__ ushort_t sK[64 * 128];       // [kv][d], 256B rows, slot ^= (row&15)
  __shared__ ushort_t sV[128 * 64];       // [d][kv], 128B rows, slot ^= (row&7)
  __shared__ ushort_t sP[4][32 * 64];     // per-wave [q][kv], 128B rows, slot ^= (row&7)

  // Q fragments (prescaled by SCALE_)
  bf16x8 qf[2][4];
#pragma unroll
  for (int m = 0; m < 2; ++m)
#pragma unroll
    for (int dk = 0; dk < 4; ++dk) {
      bf16x8 tq = *(const bf16x8*)(Qp + (long)(qbase + m * 16 + fr) * HD_ + dk * 32 + fg * 8);
#pragma unroll
      for (int j = 0; j < 8; ++j)
        tq[j] = (short)f2bf(bf2f((unsigned short)tq[j]) * SCALE_);
      qf[m][dk] = tq;
    }

  f32x4 o[2][9] = {};          // [m][0..7]=V-cols, [8]=row-sum (ones-B)
  float mx[2][4];
#pragma unroll
  for (int m = 0; m < 2; ++m)
#pragma unroll
    for (int r = 0; r < 4; ++r) mx[m][r] = -1e30f;

  bf16x8 ones;
#pragma unroll
  for (int j = 0; j < 8; ++j) ones[j] = (short)0x3F80;   // bf16 1.0

  // per-lane staging source offsets (elements), inverse-swizzled
  int kOff[4], vOff[4];
#pragma unroll
  for (int i = 0; i < 4; ++i) {
    int c = i * 4 + w;
    int kr = c * 4 + (lane >> 4);
    kOff[i] = kr * HD_ + (((lane & 15) ^ (kr & 15)) * 8);
    int vr = c * 8 + (lane >> 3);
    vOff[i] = vr * S_ + (((lane & 7) ^ (vr & 7)) * 8);
  }
  // per-lane swizzled ds_read byte offsets
  int kRd[4], vRd[2];
#pragma unroll
  for (int dk = 0; dk < 4; ++dk) kRd[dk] = fr * 256 + (((dk * 4 + fg) ^ fr) * 16);
#pragma unroll
  for (int ks = 0; ks < 2; ++ks) vRd[ks] = fr * 128 + (((ks * 4 + fg) ^ (fr & 7)) * 16);

  const int ntiles = qt * 2 + 2;
  for (int t = 0; t < ntiles; ++t) {
    const int kv0 = t * 64;
#pragma unroll
    for (int i = 0; i < 4; ++i)
      __builtin_amdgcn_global_load_lds((GAS1*)(Kp + (long)kv0 * HD_ + kOff[i]),
                                       (LAS3*)((char*)sK + (i * 4 + w) * 1024), 16, 0, 0);
#pragma unroll
    for (int i = 0; i < 4; ++i)
      __builtin_amdgcn_global_load_lds((GAS1*)(Vp + (long)kv0 + vOff[i]),
                                       (LAS3*)((char*)sV + (i * 4 + w) * 1024), 16, 0, 0);
    __syncthreads();

    if (kv0 <= qbase + 31) {           // wave-uniform: tile not fully masked
      // ---- QK^T: 16 kf reads shared by both m ----
      f32x4 sc0[4] = {}, sc1[4] = {};
#pragma unroll
      for (int n = 0; n < 4; ++n)
#pragma unroll
        for (int dk = 0; dk < 4; ++dk) {
          bf16x8 kf = *(const bf16x8*)((const char*)sK + n * 4096 + kRd[dk]);
          sc0[n] = __builtin_amdgcn_mfma_f32_16x16x32_bf16(qf[0][dk], kf, sc0[n], 0, 0, 0);
          sc1[n] = __builtin_amdgcn_mfma_f32_16x16x32_bf16(qf[1][dk], kf, sc1[n], 0, 0, 0);
        }
      if (kv0 + 63 > qbase) {          // causal mask
#pragma unroll
        for (int n = 0; n < 4; ++n) {
          int kj = kv0 + n * 16 + fr;
#pragma unroll
          for (int r = 0; r < 4; ++r) {
            int qi = qbase + fg * 4 + r;
            if (kj > qi) sc0[n][r] = -1e30f;
            if (kj > qi + 16) sc1[n][r] = -1e30f;
          }
        }
      }
      // ---- online softmax (max via shfl; sum via ones-MFMA later) ----
#pragma unroll
      for (int m = 0; m < 2; ++m) {
#pragma unroll
        for (int r = 0; r < 4; ++r) {
          f32x4* sc = (m == 0) ? sc0 : sc1;
          float tm = fmaxf(fmaxf(sc[0][r], sc[1][r]), fmaxf(sc[2][r], sc[3][r]));
          tm = fmaxf(tm, __shfl_xor(tm, 1));
          tm = fmaxf(tm, __shfl_xor(tm, 2));
          tm = fmaxf(tm, __shfl_xor(tm, 4));
          tm = fmaxf(tm, __shfl_xor(tm, 8));
          float nm = fmaxf(mx[m][r], tm);
          float sca = exp2f((mx[m][r] - nm) * LOG2E);
          mx[m][r] = nm;
#pragma unroll
          for (int n = 0; n < 4; ++n)
            sc[n][r] = exp2f((sc[n][r] - nm) * LOG2E);
#pragma unroll
          for (int df = 0; df < 9; ++df) o[m][df][r] *= sca;
          // write P (swizzled) rows m*16 + fg*4 + r
          int row = m * 16 + fg * 4 + r;
#pragma unroll
          for (int n = 0; n < 4; ++n) {
            int byteoff = row * 128 + ((((n * 2) + (fr >> 3)) ^ (row & 7)) * 16) + ((fr & 7) * 2);
            *(ushort_t*)((char*)sP[w] + byteoff) = f2bf(sc[n][r]);
          }
        }
      }
      asm volatile("s_waitcnt lgkmcnt(0)" ::: "memory");
      __builtin_amdgcn_sched_barrier(0);
      // ---- PV ----
#pragma unroll
      for (int ks = 0; ks < 2; ++ks) {
        bf16x8 pa0 = *(const bf16x8*)((const char*)sP[w] + vRd[ks]);
        bf16x8 pa1 = *(const bf16x8*)((const char*)sP[w] + 2048 + vRd[ks]);
        o[0][8] = __builtin_amdgcn_mfma_f32_16x16x32_bf16(pa0, ones, o[0][8], 0, 0, 0);
        o[1][8] = __builtin_amdgcn_mfma_f32_16x16x32_bf16(pa1, ones, o[1][8], 0, 0, 0);
#pragma unroll
        for (int df = 0; df < 8; ++df) {
          bf16x8 vf = *(const bf16x8*)((const char*)sV + df * 2048 + vRd[ks]);
          o[0][df] = __builtin_amdgcn_mfma_f32_16x16x32_bf16(pa0, vf, o[0][df], 0, 0, 0);
          o[1][df] = __builtin_amdgcn_mfma_f32_16x16x32_bf16(pa1, vf, o[1][df], 0, 0, 0);
        }
      }
    }
    __syncthreads();
  }
  // epilogue: O layout [B,S,NH,HD] == [B,S,D]
#pragma unroll
  for (int m = 0; m < 2; ++m)
#pragma unroll
    for (int df = 0; df < 8; ++df)
#pragma unroll
      for (int r = 0; r < 4; ++r) {
        int qi = qbase + m * 16 + fg * 4 + r;
        float v = o[m][df][r] / o[m][8][r];
        O[(((long)b * S_ + qi) * NH_ + h) * HD_ + df * 16 + fr] = f2bf(v);
      }
}

// ---------------- orchestration ----------------
extern "C" void kernel_launch(void* const* d_in, const int* in_sizes, int n_in,
                              void* d_out, int out_size, void* d_ws, size_t ws_size,
                              hipStream_t stream) {
  const float* hs = (const float*)d_in[0];
  const float* wqkv = (const float*)d_in[1];
  const float* wout = (const float*)d_in[2];
  const float* cosb = (const float*)d_in[3];
  const float* sinb = (const float*)d_in[4];
  char* ws = (char*)d_ws;

  ushort_t* hsB = (ushort_t*)(ws + 0);
  ushort_t* wqB = (ushort_t*)(ws + 33554432);
  ushort_t* Kb = (ushort_t*)(ws + 33554432);
  ushort_t* Vb = (ushort_t*)(ws + 41943040);
  ushort_t* Vtb = (ushort_t*)(ws + 50331648);
  ushort_t* aoB = (ushort_t*)(ws + 58720256);
  ushort_t* qkvB = (ushort_t*)(ws + 83886080);
  ushort_t* woB = (ushort_t*)(ws + 100663296);
  ushort_t* Qb = hsB;

  hipLaunchKernelGGL(f2bf_kernel, dim3(2048), dim3(256), 0, stream, hs, hsB, 16777216 / 8);
  hipLaunchKernelGGL(f2bf_kernel, dim3(2048), dim3(256), 0, stream, wqkv, wqB, 25165824 / 8);
  hipLaunchKernelGGL((gemm_bt<0>), dim3(48, 32), dim3(256), 0, stream,
                     hsB, wqB, (void*)qkvB, 4096, QKVN, 4096);
  hipLaunchKernelGGL(rope_split, dim3(4096), dim3(256), 0, stream, qkvB, cosb, sinb, Qb, Kb, Vb);
  hipLaunchKernelGGL(f2bf_kernel, dim3(2048), dim3(256), 0, stream, wout, woB, 16777216 / 8);
  hipLaunchKernelGGL(transpose_v, dim3(4, 64, 16), dim3(256), 0, stream, Vb, Vtb);
  hipLaunchKernelGGL(attn_fwd, dim3(16, 32, 2), dim3(256), 0, stream, Qb, Kb, Vtb, aoB);
  hipLaunchKernelGGL((gemm_bt<1>), dim3(32, 32), dim3(256), 0, stream,
                     aoB, woB, d_out, 4096, 4096, 4096);
}